// Round 7
// baseline (501.077 us; speedup 1.0000x reference)
//
#include <hip/hip_runtime.h>
#include <hip/hip_bf16.h>

#define N_ 16384
#define D_ 512
#define BM 256
#define BN 256
#define BK 32
#define NT (D_ / BK)    // 16 K-tiles
#define NBLK (N_ / BM)  // 64 blocks per dim
#define SLOTB 16384     // bytes per operand slot: 256 rows x 32 cols bf16

typedef __attribute__((ext_vector_type(8))) __bf16 bf16x8;
typedef __attribute__((ext_vector_type(4))) float f32x4;

#define GLDS(gptr, lptr)                                                              \
  __builtin_amdgcn_global_load_lds((const __attribute__((address_space(1))) void*)(gptr), \
                                   (__attribute__((address_space(3))) void*)(lptr), 16, 0, 0)

#define MFMA16(a, b, c) __builtin_amdgcn_mfma_f32_16x16x32_bf16((a), (b), (c), 0, 0, 0)

__device__ inline unsigned short f2bf(float f) {
  __hip_bfloat16 h = __float2bfloat16(f);
  return *reinterpret_cast<unsigned short*>(&h);
}

// ---------------- fp32 -> bf16 convert (vectorized), optional scale fold ----------------
// img gets scale * log2(e) folded in -> downstream exp/log run in base-2 domain.
__global__ void cvt_bf16_kernel(const float* __restrict__ src,
                                unsigned short* __restrict__ dst, long n,
                                const float* __restrict__ scale_p) {
  const float s = scale_p ? scale_p[0] * 1.4426950408889634f : 1.0f;
  long i = ((long)blockIdx.x * blockDim.x + threadIdx.x) * 8;
  const long stride = (long)gridDim.x * blockDim.x * 8;
  typedef __attribute__((ext_vector_type(8))) unsigned short us8;
  for (; i < n; i += stride) {
    const float4* sp = (const float4*)(src + i);
    float4 f0 = sp[0], f1 = sp[1];
    us8 v;
    v[0] = f2bf(f0.x * s); v[1] = f2bf(f0.y * s); v[2] = f2bf(f0.z * s); v[3] = f2bf(f0.w * s);
    v[4] = f2bf(f1.x * s); v[5] = f2bf(f1.y * s); v[6] = f2bf(f1.z * s); v[7] = f2bf(f1.w * s);
    *(us8*)(dst + i) = v;
  }
}

// ---- 256x256 quadrant-major 2-phase-per-tile, TRIPLE-buffered GEMM + LSE partials ----
// 8 waves (2M x 4N), wave tile 128x64. Slot T%3 is read; tile T+2 staged into slot
// (T+2)%3 which holds tile T-1 (dead >= 2 barriers ago) -> no LDS write/read race by
// construction. Counted vmcnt(4) once per tile (ph2) keeps T's own 4 stage-issues in
// flight across barriers (T4); never 0 mid-loop. Swizzle: R6-verified 64B-row
// involution (slot (row,s) holds global (row, s ^ ((row>>1)&3))), linear GLDS dest.
// T5 setprio around MFMA clusters. L2 mapping: XCD owns an 8-wide bc stripe.
__global__ __launch_bounds__(512, 2)
void gemm_lse_kernel(const unsigned short* __restrict__ A,   // log2e*scale*img bf16 [N][D]
                     const unsigned short* __restrict__ B,   // txt bf16 [N][D]
                     float2* __restrict__ rowMS,  // [NBLK(colblk)][N] (max, sumexp) base-2
                     float2* __restrict__ colMS,  // [NBLK(rowblk)][N]
                     float* __restrict__ diag) {
  __shared__ __align__(16) unsigned short AL[3][2][128][32];  // 48 KiB (slot, mhalf)
  __shared__ __align__(16) unsigned short BL[3][2][128][32];  // 48 KiB (slot, nhalf)
  __shared__ float rowb[4][256][2];  // 8 KiB
  __shared__ float colb[2][256][2];  // 4 KiB

  const int t = threadIdx.x;
  const int l = t & 63;
  const int wid = t >> 6;   // 0..7
  const int wr = wid >> 2;  // 0..1 : rows [wr*128, +128)
  const int wc = wid & 3;   // 0..3 : cols [wc*64, +64)

  // L2-resident mapping: XCD x owns bc stripe [x*8, x*8+8); br advances slowly.
  const int id = blockIdx.x;
  const int w = id >> 3;
  const int bc = (id & 7) * 8 + (w & 7);
  const int br = w >> 3;

  // staging: thread t stages 16B -> LINEAR LDS byte (half*8192 + t*16).
  // dest row = t>>2, slot chunk = t&3; global src chunk = (t&3) ^ ((row>>1)&3).
  const int srow = t >> 2;                          // 0..127
  const int scol = ((t & 3) ^ ((t >> 3) & 3)) * 8;  // elements (R6-verified)

  const unsigned short* aS = A + (size_t)(br * BM + srow) * D_ + scol;
  const unsigned short* bS = B + (size_t)(bc * BN + srow) * D_ + scol;

  // read offsets: global (row, c16=l>>4) at byte row*64 + ((c16 ^ (row>>1))&3)*16
  int offA[2][4], offB[4];
#pragma unroll
  for (int qm = 0; qm < 2; ++qm)
#pragma unroll
    for (int m = 0; m < 4; ++m) {
      const int rowh = qm * 64 + m * 16 + (l & 15);  // row within wave's 128-row half
      offA[qm][m] = wr * 8192 + rowh * 64 + ((((l >> 4) ^ (rowh >> 1)) & 3) << 4);
    }
#pragma unroll
  for (int n = 0; n < 4; ++n) {
    const int colh = (wc & 1) * 64 + n * 16 + (l & 15);  // col within 128-col nhalf
    offB[n] = (wc >> 1) * 8192 + colh * 64 + ((((l >> 4) ^ (colh >> 1)) & 3) << 4);
  }
  const char* asb = (const char*)AL;
  const char* bsb = (const char*)BL;

  f32x4 acc[8][4];
#pragma unroll
  for (int m = 0; m < 8; ++m)
#pragma unroll
    for (int n = 0; n < 4; ++n) acc[m][n] = (f32x4)0.0f;

#define STG_A(kt_, S_)                                                      \
  {                                                                         \
    GLDS(aS + (kt_)*BK, (char*)AL + (S_)*SLOTB + t * 16);                   \
    GLDS(aS + 128 * D_ + (kt_)*BK, (char*)AL + (S_)*SLOTB + 8192 + t * 16); \
  }
#define STG_B(kt_, S_)                                                      \
  {                                                                         \
    GLDS(bS + (kt_)*BK, (char*)BL + (S_)*SLOTB + t * 16);                   \
    GLDS(bS + 128 * D_ + (kt_)*BK, (char*)BL + (S_)*SLOTB + 8192 + t * 16); \
  }

  // prologue: tiles 0,1 (8 issues); wait until tile0's 4 landed (tile1's stay in flight)
  STG_A(0, 0); STG_B(0, 0);
  STG_A(1, 1); STG_B(1, 1);
  asm volatile("s_waitcnt vmcnt(4)" ::: "memory");
  __builtin_amdgcn_sched_barrier(0);
  __builtin_amdgcn_s_barrier();

#pragma unroll
  for (int T = 0; T < NT; ++T) {
    const int S = T % 3;
    const int SP = (T + 2) % 3;
    bf16x8 af[4], bf[4];

    // ---- phase 1 (qm=0): read A-q0 + all B (kept in regs), stage A halves of T+2 ----
#pragma unroll
    for (int m = 0; m < 4; ++m) af[m] = *(const bf16x8*)(asb + S * SLOTB + offA[0][m]);
#pragma unroll
    for (int n = 0; n < 4; ++n) bf[n] = *(const bf16x8*)(bsb + S * SLOTB + offB[n]);
    if (T + 2 < NT) STG_A(T + 2, SP);
    __builtin_amdgcn_s_barrier();
    asm volatile("s_waitcnt lgkmcnt(0)" ::: "memory");
    __builtin_amdgcn_sched_barrier(0);
    __builtin_amdgcn_s_setprio(1);
#pragma unroll
    for (int m = 0; m < 4; ++m)
#pragma unroll
      for (int n = 0; n < 4; ++n) acc[m][n] = MFMA16(af[m], bf[n], acc[m][n]);
    __builtin_amdgcn_s_setprio(0);
    __builtin_amdgcn_s_barrier();

    // ---- phase 2 (qm=1): read A-q1 (reuse bf regs), stage B halves of T+2 ----
#pragma unroll
    for (int m = 0; m < 4; ++m) af[m] = *(const bf16x8*)(asb + S * SLOTB + offA[1][m]);
    if (T + 2 < NT) STG_B(T + 2, SP);
    if (T <= NT - 3) {
      asm volatile("s_waitcnt vmcnt(4)" ::: "memory");  // T's 4 issues stay in flight
      __builtin_amdgcn_sched_barrier(0);
    } else if (T == NT - 2) {
      asm volatile("s_waitcnt vmcnt(0)" ::: "memory");  // drain: last tile must be ready
      __builtin_amdgcn_sched_barrier(0);
    }
    __builtin_amdgcn_s_barrier();
    asm volatile("s_waitcnt lgkmcnt(0)" ::: "memory");
    __builtin_amdgcn_sched_barrier(0);
    __builtin_amdgcn_s_setprio(1);
#pragma unroll
    for (int m = 0; m < 4; ++m)
#pragma unroll
      for (int n = 0; n < 4; ++n) acc[4 + m][n] = MFMA16(af[m], bf[n], acc[4 + m][n]);
    __builtin_amdgcn_s_setprio(0);
    __builtin_amdgcn_s_barrier();
  }
#undef STG_A
#undef STG_B

  // ---- epilogue (base-2 domain): diag, row/col online-LSE partials ----
  // C/D layout (m89-verified): row = wr*128 + m*16 + (l>>4)*4 + r, col = wc*64 + n*16 + (l&15)
  if (br == bc) {
#pragma unroll
    for (int m = 0; m < 8; ++m)
#pragma unroll
      for (int n = 0; n < 4; ++n)
#pragma unroll
        for (int r = 0; r < 4; ++r) {
          const int row = wr * 128 + m * 16 + (l >> 4) * 4 + r;
          const int col = wc * 64 + n * 16 + (l & 15);
          if (row == col) diag[br * BM + row] = acc[m][n][r];
        }
  }

  // ROW pass: row's 64 cols = {n} x 16 lanes (l&15)
#pragma unroll
  for (int m = 0; m < 8; ++m) {
#pragma unroll
    for (int r = 0; r < 4; ++r) {
      float mx = fmaxf(fmaxf(acc[m][0][r], acc[m][1][r]), fmaxf(acc[m][2][r], acc[m][3][r]));
#pragma unroll
      for (int off = 1; off < 16; off <<= 1) mx = fmaxf(mx, __shfl_xor(mx, off, 64));
      float s = 0.f;
#pragma unroll
      for (int n = 0; n < 4; ++n) s += exp2f(acc[m][n][r] - mx);
#pragma unroll
      for (int off = 1; off < 16; off <<= 1) s += __shfl_xor(s, off, 64);
      if ((l & 15) == 0) {
        const int row = wr * 128 + m * 16 + (l >> 4) * 4 + r;
        rowb[wc][row][0] = mx;
        rowb[wc][row][1] = s;
      }
    }
  }

  // COL pass: col's 128 rows = {m,r} x 4 lane-groups (l>>4)
#pragma unroll
  for (int n = 0; n < 4; ++n) {
    float mx = -1e30f;
#pragma unroll
    for (int m = 0; m < 8; ++m)
#pragma unroll
      for (int r = 0; r < 4; ++r) mx = fmaxf(mx, acc[m][n][r]);
    mx = fmaxf(mx, __shfl_xor(mx, 16, 64));
    mx = fmaxf(mx, __shfl_xor(mx, 32, 64));
    float s = 0.f;
#pragma unroll
    for (int m = 0; m < 8; ++m)
#pragma unroll
      for (int r = 0; r < 4; ++r) s += exp2f(acc[m][n][r] - mx);
    s += __shfl_xor(s, 16, 64);
    s += __shfl_xor(s, 32, 64);
    if ((l >> 4) == 0) {
      const int col = wc * 64 + n * 16 + l;
      colb[wr][col][0] = mx;
      colb[wr][col][1] = s;
    }
  }
  __syncthreads();

  // merge wave partials, write (coalesced float2)
  if (t < 256) {
    float mm = -1e30f, ss = 0.f;
#pragma unroll
    for (int wv = 0; wv < 4; ++wv) {
      float m0 = rowb[wv][t][0], s0 = rowb[wv][t][1];
      float nm = fmaxf(mm, m0);
      ss = ss * exp2f(mm - nm) + s0 * exp2f(m0 - nm);
      mm = nm;
    }
    rowMS[(size_t)bc * N_ + br * BM + t] = make_float2(mm, ss);
  } else {
    const int c = t - 256;
    float mm = -1e30f, ss = 0.f;
#pragma unroll
    for (int wv = 0; wv < 2; ++wv) {
      float m0 = colb[wv][c][0], s0 = colb[wv][c][1];
      float nm = fmaxf(mm, m0);
      ss = ss * exp2f(mm - nm) + s0 * exp2f(m0 - nm);
      mm = nm;
    }
    colMS[(size_t)br * N_ + bc * BN + c] = make_float2(mm, ss);
  }
}

// ---------------- merge partials -> per-row/col LSE2 -> partial sums (base-2) ----------
__global__ void reduce1_kernel(const float2* __restrict__ rowMS,
                               const float2* __restrict__ colMS,
                               const float* __restrict__ diag,
                               float* __restrict__ partials) {
  const int tid = blockIdx.x * blockDim.x + threadIdx.x;  // 0..32767
  float m = -1e30f, s = 0.f;
  if (tid < N_) {
    const int r = tid;
    for (int cb = 0; cb < NBLK; ++cb) {
      float2 p = rowMS[(size_t)cb * N_ + r];
      float nm = fmaxf(m, p.x);
      s = s * exp2f(m - nm) + p.y * exp2f(p.x - nm);
      m = nm;
    }
    m = m + log2f(s) - diag[r];
  } else {
    const int c = tid - N_;
    for (int rb = 0; rb < NBLK; ++rb) {
      float2 p = colMS[(size_t)rb * N_ + c];
      float nm = fmaxf(m, p.x);
      s = s * exp2f(m - nm) + p.y * exp2f(p.x - nm);
      m = nm;
    }
    m = m + log2f(s) - diag[c];
  }
  float val = m;
#pragma unroll
  for (int off = 1; off < 64; off <<= 1) val += __shfl_xor(val, off, 64);
  __shared__ float red[4];
  if ((threadIdx.x & 63) == 0) red[threadIdx.x >> 6] = val;
  __syncthreads();
  if (threadIdx.x == 0) partials[blockIdx.x] = red[0] + red[1] + red[2] + red[3];
}

__global__ void reduce2_kernel(const float* __restrict__ partials, float* __restrict__ out) {
  const int t = threadIdx.x;  // 64 threads
  float v = partials[t] + partials[t + 64];
#pragma unroll
  for (int off = 1; off < 64; off <<= 1) v += __shfl_xor(v, off, 64);
  // base-2 -> natural log (x ln2); mean over rows+cols and the 0.5 factor
  if (t == 0) out[0] = v * (0.69314718055994531f / (2.0f * (float)N_));
}

extern "C" void kernel_launch(void* const* d_in, const int* in_sizes, int n_in,
                              void* d_out, int out_size, void* d_ws, size_t ws_size,
                              hipStream_t stream) {
  const float* img = (const float*)d_in[0];
  const float* txt = (const float*)d_in[1];
  const float* scale = (const float*)d_in[2];
  float* out = (float*)d_out;

  char* ws = (char*)d_ws;
  size_t off = 0;
  unsigned short* imgB = (unsigned short*)(ws + off); off += (size_t)N_ * D_ * 2;
  unsigned short* txtB = (unsigned short*)(ws + off); off += (size_t)N_ * D_ * 2;
  float2* rowMS = (float2*)(ws + off); off += (size_t)NBLK * N_ * sizeof(float2);
  float2* colMS = (float2*)(ws + off); off += (size_t)NBLK * N_ * sizeof(float2);
  float* diag = (float*)(ws + off); off += (size_t)N_ * sizeof(float);
  float* partials = (float*)(ws + off); off += 128 * sizeof(float);
  (void)ws_size; (void)in_sizes; (void)n_in; (void)out_size;

  cvt_bf16_kernel<<<1024, 256, 0, stream>>>(img, imgB, (long)N_ * D_, scale);
  cvt_bf16_kernel<<<1024, 256, 0, stream>>>(txt, txtB, (long)N_ * D_, nullptr);
  gemm_lse_kernel<<<NBLK * NBLK, 512, 0, stream>>>(imgB, txtB, rowMS, colMS, diag);
  reduce1_kernel<<<(2 * N_) / 256, 256, 0, stream>>>(rowMS, colMS, diag, partials);
  reduce2_kernel<<<1, 64, 0, stream>>>(partials, out);
}